// Round 1
// baseline (359.132 us; speedup 1.0000x reference)
//
#include <hip/hip_runtime.h>
#include <hip/hip_bf16.h>
#include <stdint.h>

namespace {

constexpr int MTOT = 8192;   // 4 * 2048 rows of x
constexpr int NTOT = 4096;   // OUT_DIM
constexpr int KTOT = 4096;   // IN_DIM

typedef __attribute__((ext_vector_type(8))) short bf16x8;
typedef __attribute__((ext_vector_type(4))) float f32x4;

__device__ inline unsigned short to_bf16(float f) {
    union { float f; uint32_t u; } v; v.f = f;
    return (unsigned short)((v.u + 0x7FFFu + ((v.u >> 16) & 1u)) >> 16);
}

// ---- Kernel 1: fp32 -> bf16 convert of x (8 elems / thread) ----
__global__ __launch_bounds__(256) void convert_x_kernel(const float* __restrict__ x,
                                                        unsigned short* __restrict__ xb) {
    int idx = blockIdx.x * 256 + threadIdx.x;
    const f32x4* xv = reinterpret_cast<const f32x4*>(x);
    f32x4 v0 = xv[2 * idx];
    f32x4 v1 = xv[2 * idx + 1];
    union { bf16x8 v; unsigned short s[8]; } o;
    o.s[0] = to_bf16(v0.x); o.s[1] = to_bf16(v0.y);
    o.s[2] = to_bf16(v0.z); o.s[3] = to_bf16(v0.w);
    o.s[4] = to_bf16(v1.x); o.s[5] = to_bf16(v1.y);
    o.s[6] = to_bf16(v1.z); o.s[7] = to_bf16(v1.w);
    reinterpret_cast<bf16x8*>(xb)[idx] = o.v;
}

// ---- Kernel 2: W[o][i] = sum_b a[b][o/512][i/512] * s[b][o%512][i%512], bf16 out ----
// one thread per 8 consecutive i of one o (i-block never crosses a 512 boundary)
__global__ __launch_bounds__(256) void gen_w_kernel(const float* __restrict__ a,
                                                    const float* __restrict__ s,
                                                    unsigned short* __restrict__ w) {
    int idx = blockIdx.x * 256 + threadIdx.x;   // 4096 * 512 threads
    int o  = idx >> 9;          // 0..4095
    int i8 = idx & 511;         // which 8-elem block
    int i0 = i8 * 8;
    int obig = o >> 9, orow = o & 511;
    int ibig = i0 >> 9, icol = i0 & 511;

    float acc[8];
#pragma unroll
    for (int j = 0; j < 8; ++j) acc[j] = 0.f;

#pragma unroll
    for (int b = 0; b < 8; ++b) {
        float av = a[b * 64 + obig * 8 + ibig];
        const f32x4* sv = reinterpret_cast<const f32x4*>(s + b * 512 * 512 + orow * 512 + icol);
        f32x4 s0 = sv[0], s1 = sv[1];
        acc[0] += av * s0.x; acc[1] += av * s0.y; acc[2] += av * s0.z; acc[3] += av * s0.w;
        acc[4] += av * s1.x; acc[5] += av * s1.y; acc[6] += av * s1.z; acc[7] += av * s1.w;
    }
    union { bf16x8 v; unsigned short q[8]; } ov;
#pragma unroll
    for (int j = 0; j < 8; ++j) ov.q[j] = to_bf16(acc[j]);
    reinterpret_cast<bf16x8*>(w)[idx] = ov.v;
}

// ---- Kernel 3: C[m,n] = sum_k A[m,k] * B[n,k]   (m97-structure GEMM, bf16 MFMA) ----
// A: MTOT x KTOT bf16 row-major; B: NTOT x KTOT bf16 row-major; C: MTOT x NTOT f32
__global__ __launch_bounds__(256, 2)
void gemm_bt_kernel(const unsigned short* __restrict__ A,
                    const unsigned short* __restrict__ B,
                    float* __restrict__ C) {
    constexpr int BM = 128, BN = 128, BK = 64;
    __shared__ __align__(16) unsigned short As[BM * BK];
    __shared__ __align__(16) unsigned short Bs[BN * BK];

    const int nbn = NTOT / BN;            // 32
    int bid = blockIdx.x;
    int bm = bid / nbn;
    int bn = bid % nbn;

    int tid  = threadIdx.x;
    int wave = tid >> 6;                  // 0..3
    int lane = tid & 63;
    int wm = wave >> 1, wn = wave & 1;    // 2x2 wave grid, each wave does 64x64

    // staging geometry: per issue, a wave writes 8 consecutive rows (64 lanes * 16B = 1KiB)
    int srow = lane >> 3;                 // 0..7
    int scol = (lane & 7) * 8;            // elem offset within row

    const unsigned short* Ag = A + (size_t)(bm * BM) * KTOT;
    const unsigned short* Bg = B + (size_t)(bn * BN) * KTOT;

    f32x4 acc[4][4];
#pragma unroll
    for (int i = 0; i < 4; ++i)
#pragma unroll
        for (int j = 0; j < 4; ++j) acc[i][j] = (f32x4)0.f;

    for (int k0 = 0; k0 < KTOT; k0 += BK) {
        // ---- stage A,B tiles: each wave stages rows [wave*32, wave*32+32) of both ----
#pragma unroll
        for (int j = 0; j < 4; ++j) {
            int rowbase = wave * 32 + j * 8;
            const unsigned short* ga = Ag + (size_t)(rowbase + srow) * KTOT + k0 + scol;
            const unsigned short* gb = Bg + (size_t)(rowbase + srow) * KTOT + k0 + scol;
            unsigned short* la = As + rowbase * BK;   // wave-uniform LDS base
            unsigned short* lb = Bs + rowbase * BK;
            __builtin_amdgcn_global_load_lds(
                (const __attribute__((address_space(1))) void*)ga,
                (__attribute__((address_space(3))) void*)la, 16, 0, 0);
            __builtin_amdgcn_global_load_lds(
                (const __attribute__((address_space(1))) void*)gb,
                (__attribute__((address_space(3))) void*)lb, 16, 0, 0);
        }
        __syncthreads();

        // ---- compute: 2 x (8 ds_read_b128 + 16 MFMA) ----
#pragma unroll
        for (int kk = 0; kk < 2; ++kk) {
            bf16x8 af[4], bfr[4];
            int kof = kk * 32 + (lane >> 4) * 8;
            int rl  = lane & 15;
#pragma unroll
            for (int t = 0; t < 4; ++t) {
                af[t]  = *reinterpret_cast<const bf16x8*>(As + (wm * 64 + t * 16 + rl) * BK + kof);
                bfr[t] = *reinterpret_cast<const bf16x8*>(Bs + (wn * 64 + t * 16 + rl) * BK + kof);
            }
#pragma unroll
            for (int mt = 0; mt < 4; ++mt)
#pragma unroll
                for (int nt = 0; nt < 4; ++nt)
                    acc[mt][nt] = __builtin_amdgcn_mfma_f32_16x16x32_bf16(
                        af[mt], bfr[nt], acc[mt][nt], 0, 0, 0);
        }
        __syncthreads();
    }

    // ---- epilogue: C/D layout col = lane&15, row = (lane>>4)*4 + j ----
    int crow = bm * BM + wm * 64;
    int ccol = bn * BN + wn * 64;
    int cl = lane & 15;
    int rq = (lane >> 4) * 4;
#pragma unroll
    for (int mt = 0; mt < 4; ++mt)
#pragma unroll
        for (int nt = 0; nt < 4; ++nt)
#pragma unroll
            for (int j = 0; j < 4; ++j) {
                size_t r = (size_t)(crow + mt * 16 + rq + j);
                size_t c = (size_t)(ccol + nt * 16 + cl);
                C[r * NTOT + c] = acc[mt][nt][j];
            }
}

} // anonymous namespace

extern "C" void kernel_launch(void* const* d_in, const int* in_sizes, int n_in,
                              void* d_out, int out_size, void* d_ws, size_t ws_size,
                              hipStream_t stream) {
    const float* x = (const float*)d_in[0];   // (4,2048,4096) f32
    const float* a = (const float*)d_in[1];   // (8,8,8) f32
    const float* s = (const float*)d_in[2];   // (8,512,512) f32
    float* out = (float*)d_out;               // (4,2048,4096) f32

    unsigned short* xb = (unsigned short*)d_ws;                    // 64 MiB bf16 x
    unsigned short* wb = xb + (size_t)MTOT * KTOT;                 // 32 MiB bf16 W

    convert_x_kernel<<<(MTOT * KTOT / 8) / 256, 256, 0, stream>>>(x, xb);
    gen_w_kernel<<<(NTOT * KTOT / 8) / 256, 256, 0, stream>>>(a, s, wb);
    gemm_bt_kernel<<<(MTOT / 128) * (NTOT / 128), 256, 0, stream>>>(xb, wb, out);
}